// Round 3
// baseline (558.320 us; speedup 1.0000x reference)
//
#include <hip/hip_runtime.h>
#include <stdint.h>

// out = x @ dequant(W)^T + bias
// x: [M,K] fp32 (M=B*S=8192), W_q: [N,K] int32 codes in [0,4),
// scale/zp: [N,K/G] fp32 (G=64), bias: [N] fp32, out: [M,N] fp32.
//
// R5: (a) gemm: register fragment double-buffering at 16-MFMA cluster
// granularity on top of R4's 256x256/TK=64 schedule — ds_reads for cluster
// c+1 issue during cluster c's MFMAs, so lgkm waits leave the critical
// path. lgkmcnt(0) before each barrier (WAR safety vs global_load_lds
// writes), counted vmcnt(4) at both barriers (stages: c2 -> (t+1).h1,
// c4 -> (t+2).h0). (b) prep: grid-stride 2048 blocks, 8 elems/thread/iter
// (32B load, 16B store) — old version was 49k tiny blocks at 24B/thread.

typedef __attribute__((ext_vector_type(4))) float  f32x4;
typedef __attribute__((ext_vector_type(4))) int    i32x4;
typedef __attribute__((ext_vector_type(8))) __bf16 bf16x8;
typedef __attribute__((ext_vector_type(8))) unsigned short u16x8;

__device__ __forceinline__ unsigned short f2bf(float f) {
  unsigned u = __builtin_bit_cast(unsigned, f);
  u += 0x7fffu + ((u >> 16) & 1u);   // round-to-nearest-even
  return (unsigned short)(u >> 16);
}

__device__ __forceinline__ void async16(const void* g, void* l) {
  __builtin_amdgcn_global_load_lds(
      (const __attribute__((address_space(1))) unsigned int*)g,
      (__attribute__((address_space(3))) unsigned int*)l, 16, 0, 0);
}

// ---------------- fused prepass: x->bf16 and dequant W->bf16 ----------------
__global__ __launch_bounds__(256) void prep_kernel(
    const float* __restrict__ x, unsigned short* __restrict__ xb, int xunits,
    const int* __restrict__ wq, const float* __restrict__ scale,
    const float* __restrict__ zp, unsigned short* __restrict__ wb,
    int wunits, int K, int G, int ng) {
  const int stride = gridDim.x * 256;
  const int i0 = blockIdx.x * 256 + threadIdx.x;
  // x: 8 floats per iteration -> 8 bf16 (one b128 store)
  for (int u = i0; u < xunits; u += stride) {
    const f32x4* xp = (const f32x4*)x + (size_t)u * 2;
    f32x4 a = xp[0], b = xp[1];
    u16x8 o;
    o[0] = f2bf(a[0]); o[1] = f2bf(a[1]); o[2] = f2bf(a[2]); o[3] = f2bf(a[3]);
    o[4] = f2bf(b[0]); o[5] = f2bf(b[1]); o[6] = f2bf(b[2]); o[7] = f2bf(b[3]);
    *((u16x8*)xb + u) = o;
  }
  // w: 8 codes per iteration, all within one (n, group) since 8 | G
  for (int u = i0; u < wunits; u += stride) {
    int k8 = u * 8;
    int n = k8 / K, kk = k8 % K;
    int g = kk / G;
    float s  = scale[(size_t)n * ng + g];
    float bz = -zp[(size_t)n * ng + g] * s;   // w = q*s + bz
    const i32x4* wp = (const i32x4*)wq + (size_t)u * 2;
    i32x4 qa = wp[0], qb = wp[1];
    u16x8 o;
    o[0] = f2bf((float)qa[0] * s + bz); o[1] = f2bf((float)qa[1] * s + bz);
    o[2] = f2bf((float)qa[2] * s + bz); o[3] = f2bf((float)qa[3] * s + bz);
    o[4] = f2bf((float)qb[0] * s + bz); o[5] = f2bf((float)qb[1] * s + bz);
    o[6] = f2bf((float)qb[2] * s + bz); o[7] = f2bf((float)qb[3] * s + bz);
    *((u16x8*)wb + u) = o;
  }
}

// ---------------- main GEMM: C[M,N] = A[M,K] * B[N,K]^T + bias ----------------
#define BM 256
#define BN 256
#define TK 64            // K per tile = two k32 half-tiles
#define REG 8192         // elems per half-tile region: 256 rows * 32 cols

__global__ __launch_bounds__(512, 2) void gemm_bt_kernel(
    const unsigned short* __restrict__ A,   // M x K bf16
    const unsigned short* __restrict__ B,   // N x K bf16
    const float* __restrict__ bias,
    float* __restrict__ C, int M, int N, int K) {
  // [parity][khalf] 16 KB regions: 64 KB per operand, 128 KB total.
  __shared__ unsigned short As[4 * REG];
  __shared__ unsigned short Bs[4 * REG];

  const int tid  = threadIdx.x;
  const int lane = tid & 63;
  const int wave = tid >> 6;                // 8 waves: 2 (M) x 4 (N)
  const int wm = wave >> 2, wn = wave & 3;  // wave tile: 128 (M) x 64 (N)
  const int q = lane >> 4, r = lane & 15;   // MFMA k-group / row-in-16

  // XCD-aware bijective swizzle (nwg % 8 == 0).
  int id = blockIdx.x;
  {
    int nwg = gridDim.x;
    if ((nwg & 7) == 0) id = (id & 7) * (nwg >> 3) + (id >> 3);
  }
  const int nbx = N / BN;
  const int m0 = (id / nbx) * BM;
  const int n0 = (id % nbx) * BN;

  // Staging: thread tid owns LDS (row = tid>>2 within 128-row shot,
  // chunk = tid&3); global source pre-swizzled so stored chunk s of row
  // holds global chunk s ^ ((row>>1)&3).
  const int srow = tid >> 2;                      // 0..127
  const int gch  = (tid & 3) ^ ((tid >> 3) & 3);  // (tid&3) ^ ((srow>>1)&3)
  const unsigned short* aG = A + (size_t)(m0 + srow) * K + gch * 8;
  const unsigned short* bG = B + (size_t)(n0 + srow) * K + gch * 8;
  const size_t rb = (size_t)128 * K;              // shot-1 row offset

  unsigned short* aS = As + tid * 8;
  unsigned short* bS = Bs + tid * 8;

  // Read side: global chunk q of row R lives at stored chunk q ^ ((R>>1)&3);
  // frag rows are 16-aligned + r, so key = (r>>1)&3 (const per lane).
  const int qc8 = (q ^ ((r >> 1) & 3)) * 8;
  const unsigned short* aRd = As + (wm * 128 + r) * 32 + qc8;  // + mi*512
  const unsigned short* bRd = Bs + (wn * 64  + r) * 32 + qc8;  // + nj*512

  f32x4 acc[8][4] = {};
  const int NT = K / TK;

  // One half-tile stage = 2 global_load_lds per thread (128 rows per shot).
#define STG(S, G, par, kh, kk) { \
    unsigned short* l = (S) + ((par) * 2 + (kh)) * REG; \
    async16((G) + (kk) + (kh) * 32, l); \
    async16((G) + rb + (kk) + (kh) * 32, l + 4096); }

#define RD4(DST, PTR, O) \
    _Pragma("unroll") \
    for (int i_ = 0; i_ < 4; ++i_) \
      (DST)[i_] = *(const bf16x8*)&(PTR)[((O) + i_) * 512];

#define MF16(AF, BF, RO) \
    __builtin_amdgcn_s_setprio(1); \
    _Pragma("unroll") \
    for (int i_ = 0; i_ < 4; ++i_) \
      _Pragma("unroll") \
      for (int j_ = 0; j_ < 4; ++j_) \
        acc[(RO) + i_][j_] = __builtin_amdgcn_mfma_f32_16x16x32_bf16( \
            (AF)[i_], (BF)[j_], acc[(RO) + i_][j_], 0, 0, 0); \
    __builtin_amdgcn_s_setprio(0);

  bf16x8 afA[4], afB[4], bfP[4], bfQ[4];

  // Prologue: stage tile0 (h0,h1) + tile1.h0; wait tile0; read (0,h0) frags.
  STG(aS, aG, 0, 0, 0) STG(bS, bG, 0, 0, 0)
  STG(aS, aG, 0, 1, 0) STG(bS, bG, 0, 1, 0)
  if (NT > 1) { STG(aS, aG, 1, 0, TK) STG(bS, bG, 1, 0, TK) }
  if (NT > 1) asm volatile("s_waitcnt vmcnt(4)" ::: "memory");
  else        asm volatile("s_waitcnt vmcnt(0)" ::: "memory");
  __builtin_amdgcn_s_barrier();
  RD4(afA, aRd, 0)
  RD4(bfP, bRd, 0)

#pragma unroll 1
  for (int t = 0; t < NT; ++t) {
    const int par = t & 1, nxt = par ^ 1;
    const bool pf = (t + 1 < NT);
    const int kk1 = (t + 1) * TK;
    const unsigned short* a0 = aRd + (par * 2 + 0) * REG;
    const unsigned short* a1 = aRd + (par * 2 + 1) * REG;
    const unsigned short* b1 = bRd + (par * 2 + 1) * REG;

    // c1: read afB <- h0.a47 ; MFMA(afA x bfP -> acc[0..3])
    RD4(afB, a0, 4)
    MF16(afA, bfP, 0)

    // c2: stage (t+1).h1 ; read afA <- h1.a03, bfQ <- h1.b ;
    //     MFMA(afB x bfP -> acc[4..7])
    if (pf) { STG(aS, aG, nxt, 1, kk1) STG(bS, bG, nxt, 1, kk1) }
    RD4(afA, a1, 0)
    RD4(bfQ, b1, 0)
    MF16(afB, bfP, 4)

    // mid barrier: drain (t+1).h0 (leave (t+1).h1); all ds_reads complete
    // (lgkmcnt(0)) so post-barrier stages can't overwrite in-flight reads.
    if (pf) asm volatile("s_waitcnt vmcnt(4) lgkmcnt(0)" ::: "memory");
    else    asm volatile("s_waitcnt vmcnt(0) lgkmcnt(0)" ::: "memory");
    __builtin_amdgcn_s_barrier();

    // c3: read afB <- h1.a47 ; MFMA(afA x bfQ -> acc[0..3])
    RD4(afB, a1, 4)
    MF16(afA, bfQ, 0)

    // c4: read (t+1,h0) frags (LDS-ready since mid barrier) ;
    //     stage (t+2).h0 ; MFMA(afB x bfQ -> acc[4..7])
    if (pf) {
      const unsigned short* na0 = aRd + (nxt * 2) * REG;
      const unsigned short* nb0 = bRd + (nxt * 2) * REG;
      RD4(afA, na0, 0)
      RD4(bfP, nb0, 0)
    }
    if (t + 2 < NT) {
      STG(aS, aG, par, 0, (t + 2) * TK) STG(bS, bG, par, 0, (t + 2) * TK)
    }
    MF16(afB, bfQ, 4)

    // tile barrier: drain (t+1).h1 (leave (t+2).h0)
    if (pf) {
      if (t + 2 < NT) asm volatile("s_waitcnt vmcnt(4) lgkmcnt(0)" ::: "memory");
      else            asm volatile("s_waitcnt vmcnt(0) lgkmcnt(0)" ::: "memory");
      __builtin_amdgcn_s_barrier();
    }
  }

  // epilogue: C/D layout col = lane&15, row = quad*4 + reg
  float bv[4];
#pragma unroll
  for (int j = 0; j < 4; ++j) bv[j] = bias[n0 + wn * 64 + j * 16 + r];
#pragma unroll
  for (int i = 0; i < 8; ++i) {
    int mbase = m0 + wm * 128 + i * 16 + q * 4;
#pragma unroll
    for (int e = 0; e < 4; ++e) {
      float* crow = C + (size_t)(mbase + e) * N + n0 + wn * 64 + r;
#pragma unroll
      for (int j = 0; j < 4; ++j)
        crow[j * 16] = acc[i][j][e] + bv[j];
    }
  }
}

// ---------------- correctness fallback ----------------
__global__ __launch_bounds__(256) void naive_kernel(
    const float* __restrict__ x, const int* __restrict__ wq,
    const float* __restrict__ scale, const float* __restrict__ zp,
    const float* __restrict__ bias, float* __restrict__ out,
    int M, int N, int K, int G) {
  int idx = blockIdx.x * 256 + threadIdx.x;
  if (idx >= M * N) return;
  int m = idx / N, n = idx % N;
  const float* xr = x + (size_t)m * K;
  const int* wr = wq + (size_t)n * K;
  int ng = K / G;
  float acc = 0.f;
  for (int g = 0; g < ng; ++g) {
    float s = scale[(size_t)n * ng + g];
    float b = -zp[(size_t)n * ng + g] * s;
    for (int k = 0; k < G; ++k)
      acc += xr[g * G + k] * ((float)wr[g * G + k] * s + b);
  }
  out[idx] = acc + bias[n];
}

extern "C" void kernel_launch(void* const* d_in, const int* in_sizes, int n_in,
                              void* d_out, int out_size, void* d_ws, size_t ws_size,
                              hipStream_t stream) {
  const float* x     = (const float*)d_in[0];
  const int*   wq    = (const int*)d_in[1];
  const float* scale = (const float*)d_in[2];
  const float* zp    = (const float*)d_in[3];
  const float* bias  = (const float*)d_in[4];
  float* out = (float*)d_out;

  const int N  = in_sizes[4];
  const int K  = in_sizes[1] / N;
  const int ng = in_sizes[2] / N;
  const int G  = K / ng;
  const int M  = in_sizes[0] / K;

  size_t xb_bytes = (size_t)M * K * 2;
  size_t wb_bytes = (size_t)N * K * 2;
  bool divisible = (M % BM == 0) && (N % BN == 0) && (K % TK == 0) &&
                   (G % 8 == 0);
  if (ws_size < xb_bytes + wb_bytes || !divisible) {
    int total = M * N;
    naive_kernel<<<dim3((total + 255) / 256), dim3(256), 0, stream>>>(
        x, wq, scale, zp, bias, out, M, N, K, G);
    return;
  }

  unsigned short* xb = (unsigned short*)d_ws;
  unsigned short* wb = (unsigned short*)((char*)d_ws + xb_bytes);

  int xunits = M * K / 8;
  int wunits = N * K / 8;
  prep_kernel<<<dim3(2048), dim3(256), 0, stream>>>(
      x, xb, xunits, wq, scale, zp, wb, wunits, K, G, ng);

  dim3 grid((M / BM) * (N / BN));
  gemm_bt_kernel<<<grid, dim3(512), 0, stream>>>(xb, wb, bias, out, M, N, K);
}

// Round 4
// 531.462 us; speedup vs baseline: 1.0505x; 1.0505x over previous
//
#include <hip/hip_runtime.h>
#include <stdint.h>

// out = x @ dequant(W)^T + bias
// x: [M,K] fp32 (M=B*S=8192), W_q: [N,K] int32 codes in [0,4),
// scale/zp: [N,K/G] fp32 (G=64), bias: [N] fp32, out: [M,N] fp32.
//
// R6: faithful m201 8-phase port. 256x256, TK=64, 8 waves (2M x 4N).
// LDS [par][half] regions of 128x64 bf16 (16 KB); wave reads exactly one
// A-half (wm) and one B-half (wn>>1) -> WAVE-SPECIALIZED staging: each wave
// stages only the two regions it reads (4+4 gload_lds per tile), so the
// tile-end vmcnt(0) drains loads issued 2.5-3 phases earlier (~800 cy cover).
// 4 phases per tile, each {ds_reads, stage, barrier, lgkmcnt(0), setprio,
// 16 MFMA, setprio, barrier} — m201's per-phase interleave (m196's lever).
// 8-chunk row-XOR swizzle (chunk ^= row&7 on 128B rows): uniform 8
// words/bank per wave b128 access (minimum rounds, zero conflict).

typedef __attribute__((ext_vector_type(4))) float  f32x4;
typedef __attribute__((ext_vector_type(4))) int    i32x4;
typedef __attribute__((ext_vector_type(8))) __bf16 bf16x8;
typedef __attribute__((ext_vector_type(8))) unsigned short u16x8;

__device__ __forceinline__ unsigned short f2bf(float f) {
  unsigned u = __builtin_bit_cast(unsigned, f);
  u += 0x7fffu + ((u >> 16) & 1u);   // round-to-nearest-even
  return (unsigned short)(u >> 16);
}

__device__ __forceinline__ void async16(const void* g, void* l) {
  __builtin_amdgcn_global_load_lds(
      (const __attribute__((address_space(1))) unsigned int*)g,
      (__attribute__((address_space(3))) unsigned int*)l, 16, 0, 0);
}

// ---------------- fused prepass: x->bf16 and dequant W->bf16 ----------------
__global__ __launch_bounds__(256) void prep_kernel(
    const float* __restrict__ x, unsigned short* __restrict__ xb, int xunits,
    const int* __restrict__ wq, const float* __restrict__ scale,
    const float* __restrict__ zp, unsigned short* __restrict__ wb,
    int wunits, int K, int G, int ng) {
  const int stride = gridDim.x * 256;
  const int i0 = blockIdx.x * 256 + threadIdx.x;
  for (int u = i0; u < xunits; u += stride) {
    const f32x4* xp = (const f32x4*)x + (size_t)u * 2;
    f32x4 a = xp[0], b = xp[1];
    u16x8 o;
    o[0] = f2bf(a[0]); o[1] = f2bf(a[1]); o[2] = f2bf(a[2]); o[3] = f2bf(a[3]);
    o[4] = f2bf(b[0]); o[5] = f2bf(b[1]); o[6] = f2bf(b[2]); o[7] = f2bf(b[3]);
    *((u16x8*)xb + u) = o;
  }
  for (int u = i0; u < wunits; u += stride) {
    int k8 = u * 8;
    int n = k8 / K, kk = k8 % K;
    int g = kk / G;
    float s  = scale[(size_t)n * ng + g];
    float bz = -zp[(size_t)n * ng + g] * s;   // w = q*s + bz
    const i32x4* wp = (const i32x4*)wq + (size_t)u * 2;
    i32x4 qa = wp[0], qb = wp[1];
    u16x8 o;
    o[0] = f2bf((float)qa[0] * s + bz); o[1] = f2bf((float)qa[1] * s + bz);
    o[2] = f2bf((float)qa[2] * s + bz); o[3] = f2bf((float)qa[3] * s + bz);
    o[4] = f2bf((float)qb[0] * s + bz); o[5] = f2bf((float)qb[1] * s + bz);
    o[6] = f2bf((float)qb[2] * s + bz); o[7] = f2bf((float)qb[3] * s + bz);
    *((u16x8*)wb + u) = o;
  }
}

// ---------------- main GEMM: C[M,N] = A[M,K] * B[N,K]^T + bias ----------------
#define BM 256
#define BN 256
#define TK 64
#define RSZ (128 * 64)   // region elems (128 rows x 64 cols = 16 KB)

__global__ __launch_bounds__(512, 2) void gemm_bt_kernel(
    const unsigned short* __restrict__ A,   // M x K bf16
    const unsigned short* __restrict__ B,   // N x K bf16
    const float* __restrict__ bias,
    float* __restrict__ C, int M, int N, int K) {
  // [par][half] regions: 64 KB per operand, 128 KB total.
  __shared__ unsigned short As[4 * RSZ];
  __shared__ unsigned short Bs[4 * RSZ];

  const int tid  = threadIdx.x;
  const int lane = tid & 63;
  const int wave = tid >> 6;                // 8 waves: 2 (M) x 4 (N)
  const int wm = wave >> 2, wn = wave & 3;  // wave tile: 128 (M) x 64 (N)
  const int q = lane >> 4, r = lane & 15;   // MFMA k-quad / row-in-16

  // XCD-aware bijective swizzle (nwg % 8 == 0).
  int id = blockIdx.x;
  {
    int nwg = gridDim.x;
    if ((nwg & 7) == 0) id = (id & 7) * (nwg >> 3) + (id >> 3);
  }
  const int nbx = N / BN;
  const int m0 = (id / nbx) * BM;
  const int n0 = (id % nbx) * BN;

  // Wave-specialized staging groups:
  //  A-half wm staged by the 4 waves with that wm (wgA = wave&3 = quarter).
  //  B-half bh=wn>>1 staged by its 4 waves (wgB in {0..3}).
  const int wgA = wave & 3;
  const int bh  = wn >> 1;
  const int wgB = (wave & 1) | ((wave >> 2) << 1);
  // One gload covers 8 rows x 64 cols: lane l -> row +(l>>3), chunk l&7,
  // pre-swizzled global chunk = (l&7) ^ ((l>>3)&7) (row&7 key, 8-row period).
  const int lr8 = lane >> 3;
  const int gc  = (lane & 7) ^ (lr8 & 7);
  const unsigned short* aGbase =
      A + (size_t)(m0 + wm * 128 + wgA * 32 + lr8) * K + gc * 8;
  const unsigned short* bGbase =
      B + (size_t)(n0 + bh * 128 + wgB * 32 + lr8) * K + gc * 8;

#define STG_A(np, kk) { \
    unsigned short* d = As + ((np) * 2 + wm) * RSZ + wgA * 2048 + (lane << 3); \
    const unsigned short* g = aGbase + (kk); \
    async16(g,                  d);        \
    async16(g +  8 * (size_t)K, d +  512); \
    async16(g + 16 * (size_t)K, d + 1024); \
    async16(g + 24 * (size_t)K, d + 1536); }

#define STG_B(np, kk) { \
    unsigned short* d = Bs + ((np) * 2 + bh) * RSZ + wgB * 2048 + (lane << 3); \
    const unsigned short* g = bGbase + (kk); \
    async16(g,                  d);        \
    async16(g +  8 * (size_t)K, d +  512); \
    async16(g + 16 * (size_t)K, d + 1024); \
    async16(g + 24 * (size_t)K, d + 1536); }

  // Read side: global chunk c of local row R stored at chunk c ^ (R&7);
  // frag rows = 16*mi + r (A) / (wn&1)*64 + 16*nj + r (B) -> key = r&7.
  const int key  = r & 7;
  const int cho0 = ((q) ^ key) * 8;        // ks=0 chunk q
  const int cho1 = ((4 + q) ^ key) * 8;    // ks=1 chunk 4+q
  const int aoff0 = r * 64 + cho0, aoff1 = r * 64 + cho1;
  const int boff0 = ((wn & 1) * 64 + r) * 64 + cho0;
  const int boff1 = ((wn & 1) * 64 + r) * 64 + cho1;

  f32x4 acc[8][4] = {};
  const int NT = K / TK;

  // Prologue: stage tile 0 (own regions), drain, sync.
  STG_A(0, 0) STG_B(0, 0)
  asm volatile("s_waitcnt vmcnt(0)" ::: "memory");
  __builtin_amdgcn_s_barrier();
  asm volatile("" ::: "memory");

#pragma unroll 1
  for (int t = 0; t < NT; ++t) {
    const int par = t & 1, np = par ^ 1;
    const bool pf = (t + 1 < NT);
    const int kk1 = (t + 1) * TK;
    const unsigned short* Ar = As + (par * 2 + wm) * RSZ;
    const unsigned short* Br = Bs + (par * 2 + bh) * RSZ;

    bf16x8 bb0[4], bb1[4];   // b-frags: read once, live all 4 phases

    // ---------------- phase 0: mi 0,1 (+ all b-frags) ----------------
    {
      bf16x8 aa0[2], aa1[2];
#pragma unroll
      for (int nj = 0; nj < 4; ++nj) {
        bb0[nj] = *(const bf16x8*)&Br[nj * 1024 + boff0];
        bb1[nj] = *(const bf16x8*)&Br[nj * 1024 + boff1];
      }
#pragma unroll
      for (int m2 = 0; m2 < 2; ++m2) {
        aa0[m2] = *(const bf16x8*)&Ar[m2 * 1024 + aoff0];
        aa1[m2] = *(const bf16x8*)&Ar[m2 * 1024 + aoff1];
      }
      if (pf) STG_A(np, kk1)
      asm volatile("s_waitcnt lgkmcnt(8)" ::: "memory");
      __builtin_amdgcn_s_barrier();
      asm volatile("s_waitcnt lgkmcnt(0)" ::: "memory");
      __builtin_amdgcn_s_setprio(1);
#pragma unroll
      for (int m2 = 0; m2 < 2; ++m2)
#pragma unroll
        for (int nj = 0; nj < 4; ++nj) {
          acc[m2][nj] = __builtin_amdgcn_mfma_f32_16x16x32_bf16(
              aa0[m2], bb0[nj], acc[m2][nj], 0, 0, 0);
          acc[m2][nj] = __builtin_amdgcn_mfma_f32_16x16x32_bf16(
              aa1[m2], bb1[nj], acc[m2][nj], 0, 0, 0);
        }
      __builtin_amdgcn_s_setprio(0);
      asm volatile("" ::: "memory");
      __builtin_amdgcn_s_barrier();
      asm volatile("" ::: "memory");
    }

    // ---------------- phases 1..3: mi (2p, 2p+1) ----------------
#pragma unroll
    for (int p = 1; p < 4; ++p) {
      bf16x8 aa0[2], aa1[2];
#pragma unroll
      for (int m2 = 0; m2 < 2; ++m2) {
        aa0[m2] = *(const bf16x8*)&Ar[(2 * p + m2) * 1024 + aoff0];
        aa1[m2] = *(const bf16x8*)&Ar[(2 * p + m2) * 1024 + aoff1];
      }
      if (p == 1 && pf) STG_B(np, kk1)
      __builtin_amdgcn_s_barrier();
      asm volatile("s_waitcnt lgkmcnt(0)" ::: "memory");
      __builtin_amdgcn_s_setprio(1);
#pragma unroll
      for (int m2 = 0; m2 < 2; ++m2)
#pragma unroll
        for (int nj = 0; nj < 4; ++nj) {
          acc[2 * p + m2][nj] = __builtin_amdgcn_mfma_f32_16x16x32_bf16(
              aa0[m2], bb0[nj], acc[2 * p + m2][nj], 0, 0, 0);
          acc[2 * p + m2][nj] = __builtin_amdgcn_mfma_f32_16x16x32_bf16(
              aa1[m2], bb1[nj], acc[2 * p + m2][nj], 0, 0, 0);
        }
      __builtin_amdgcn_s_setprio(0);
      asm volatile("" ::: "memory");
      // Tile end: drain own stages (issued 2.5-3 phases ago) before the
      // barrier that releases next-tile reads.
      if (p == 3) asm volatile("s_waitcnt vmcnt(0)" ::: "memory");
      __builtin_amdgcn_s_barrier();
      asm volatile("" ::: "memory");
    }
  }

  // epilogue: C/D layout col = lane&15, row = quad*4 + reg
  float bv[4];
#pragma unroll
  for (int j = 0; j < 4; ++j) bv[j] = bias[n0 + wn * 64 + j * 16 + r];
#pragma unroll
  for (int i = 0; i < 8; ++i) {
    int mbase = m0 + wm * 128 + i * 16 + q * 4;
#pragma unroll
    for (int e = 0; e < 4; ++e) {
      float* crow = C + (size_t)(mbase + e) * N + n0 + wn * 64 + r;
#pragma unroll
      for (int j = 0; j < 4; ++j)
        crow[j * 16] = acc[i][j][e] + bv[j];
    }
  }
}

// ---------------- correctness fallback ----------------
__global__ __launch_bounds__(256) void naive_kernel(
    const float* __restrict__ x, const int* __restrict__ wq,
    const float* __restrict__ scale, const float* __restrict__ zp,
    const float* __restrict__ bias, float* __restrict__ out,
    int M, int N, int K, int G) {
  int idx = blockIdx.x * 256 + threadIdx.x;
  if (idx >= M * N) return;
  int m = idx / N, n = idx % N;
  const float* xr = x + (size_t)m * K;
  const int* wr = wq + (size_t)n * K;
  int ng = K / G;
  float acc = 0.f;
  for (int g = 0; g < ng; ++g) {
    float s = scale[(size_t)n * ng + g];
    float b = -zp[(size_t)n * ng + g] * s;
    for (int k = 0; k < G; ++k)
      acc += xr[g * G + k] * ((float)wr[g * G + k] * s + b);
  }
  out[idx] = acc + bias[n];
}

extern "C" void kernel_launch(void* const* d_in, const int* in_sizes, int n_in,
                              void* d_out, int out_size, void* d_ws, size_t ws_size,
                              hipStream_t stream) {
  const float* x     = (const float*)d_in[0];
  const int*   wq    = (const int*)d_in[1];
  const float* scale = (const float*)d_in[2];
  const float* zp    = (const float*)d_in[3];
  const float* bias  = (const float*)d_in[4];
  float* out = (float*)d_out;

  const int N  = in_sizes[4];
  const int K  = in_sizes[1] / N;
  const int ng = in_sizes[2] / N;
  const int G  = K / ng;
  const int M  = in_sizes[0] / K;

  size_t xb_bytes = (size_t)M * K * 2;
  size_t wb_bytes = (size_t)N * K * 2;
  bool divisible = (M % BM == 0) && (N % BN == 0) && (K % TK == 0) &&
                   (G % 8 == 0);
  if (ws_size < xb_bytes + wb_bytes || !divisible) {
    int total = M * N;
    naive_kernel<<<dim3((total + 255) / 256), dim3(256), 0, stream>>>(
        x, wq, scale, zp, bias, out, M, N, K, G);
    return;
  }

  unsigned short* xb = (unsigned short*)d_ws;
  unsigned short* wb = (unsigned short*)((char*)d_ws + xb_bytes);

  int xunits = M * K / 8;
  int wunits = N * K / 8;
  prep_kernel<<<dim3(2048), dim3(256), 0, stream>>>(
      x, xb, xunits, wq, scale, zp, wb, wunits, K, G, ng);

  dim3 grid((M / BM) * (N / BN));
  gemm_bt_kernel<<<grid, dim3(512), 0, stream>>>(xb, wb, bias, out, M, N, K);
}